// Round 2
// baseline (437.322 us; speedup 1.0000x reference)
//
#include <hip/hip_runtime.h>

// FWHT-1024 per row of (65536, 1024) fp32, fused with out = fwht(x)/32 * scale + shift.
//
// One wave per row, 16 floats/lane. The FWHT is a tensor product of 10
// independent bit-butterflies, so stage order is free. We pick layouts so
// EVERY butterfly is register-local, using 2 wave-private LDS transposes
// instead of 96 ds_bpermute shuffles (R0 was shuffle-stall bound: 425 us
// vs ~90 us HBM floor).
//
//   phase 1: e = j*256 + lane*4 + r   (reg j=bits{9,8}, r=bits{1,0})
//            -> butterflies on bits {0,1} (in-float4) and {8,9} (cross-reg)
//   T1:      LDS write natural / read 16-consecutive
//   phase 2: e = lane*16 + (k*4+r)    (local bits {3..0})
//            -> butterflies on bits {2,3}
//   T2:      LDS write back / strided read
//   phase 3: e = (lane>>4)*256 + r16*16 + (lane&15)  (local bits {7..4})
//            -> butterflies on bits {4,5,6,7}, then epilogue.
//
// LDS addressing: addr(e) = (e>>4)*20 + (e>>8)*8 + (e&15)  [dwords]
//   - keeps 16-float rows contiguous (b128-friendly, 16B aligned: all
//     term multiples of 4 dwords)
//   - row stride 20 (coprime-ish rotation: bases 0,20,8,28,16,4,24,12 mod 32)
//     and +8 per 256-block make every pattern <=2-way bank aliased (free).
// Max dword index = 328*3 + 20*15 + 15 = 1299 -> 1300 dwords/wave.

constexpr int SIZE = 1024;
constexpr float INV_SQRT = 0.03125f; // 1/sqrt(1024)

__global__ __launch_bounds__(256) void fwht1024_kernel(
    const float* __restrict__ x,
    const float* __restrict__ scale,
    const float* __restrict__ shift,
    float* __restrict__ out,
    int nrows)
{
    __shared__ float lds[4][1300];

    const int wave = threadIdx.x >> 6;
    const int lane = threadIdx.x & 63;
    const int row  = blockIdx.x * 4 + wave;
    if (row >= nrows) return;

    float* __restrict__ sm = lds[wave];
    const float* __restrict__ xr = x + (size_t)row * SIZE;

    // ---- load: reg j = bits{9,8}, lane = bits{7..2}, r = bits{1,0} ----
    float v[4][4];
    #pragma unroll
    for (int j = 0; j < 4; ++j) {
        const float4 t = *reinterpret_cast<const float4*>(xr + 256 * j + 4 * lane);
        v[j][0] = t.x; v[j][1] = t.y; v[j][2] = t.z; v[j][3] = t.w;
    }

    // ---- phase 1a: bits {0,1} ----
    #pragma unroll
    for (int j = 0; j < 4; ++j) {
        const float a = v[j][0], b = v[j][1], c = v[j][2], d = v[j][3];
        const float ab = a + b, amb = a - b, cd = c + d, cmd = c - d;
        v[j][0] = ab + cd; v[j][1] = amb + cmd;
        v[j][2] = ab - cd; v[j][3] = amb - cmd;
    }
    // ---- phase 1b: bits {8,9} (cross-register) ----
    #pragma unroll
    for (int r = 0; r < 4; ++r) {
        const float a = v[0][r], b = v[1][r], c = v[2][r], d = v[3][r];
        const float ab = a + b, amb = a - b, cd = c + d, cmd = c - d;
        v[0][r] = ab + cd; v[1][r] = amb + cmd;
        v[2][r] = ab - cd; v[3][r] = amb - cmd;
    }

    // ---- T1 write: natural order, padded. e = 256j + 4*lane + r
    //      addr = 328j + 20*(lane>>2) + 4*(lane&3)
    const int wbase = 20 * (lane >> 2) + 4 * (lane & 3);
    #pragma unroll
    for (int j = 0; j < 4; ++j) {
        float4 t; t.x = v[j][0]; t.y = v[j][1]; t.z = v[j][2]; t.w = v[j][3];
        *reinterpret_cast<float4*>(sm + 328 * j + wbase) = t;
    }

    // ---- T1 read: e = 16*lane + (4k + r), addr = 20*lane + 8*(lane>>4) + i
    const int rbase = 20 * lane + 8 * (lane >> 4);
    #pragma unroll
    for (int k = 0; k < 4; ++k) {
        const float4 t = *reinterpret_cast<const float4*>(sm + rbase + 4 * k);
        v[k][0] = t.x; v[k][1] = t.y; v[k][2] = t.z; v[k][3] = t.w;
    }

    // ---- phase 2: bits {2,3} (cross-register k) ----
    #pragma unroll
    for (int r = 0; r < 4; ++r) {
        const float a = v[0][r], b = v[1][r], c = v[2][r], d = v[3][r];
        const float ab = a + b, amb = a - b, cd = c + d, cmd = c - d;
        v[0][r] = ab + cd; v[1][r] = amb + cmd;
        v[2][r] = ab - cd; v[3][r] = amb - cmd;
    }

    // ---- T2 write back (same addresses as T1 read) ----
    #pragma unroll
    for (int k = 0; k < 4; ++k) {
        float4 t; t.x = v[k][0]; t.y = v[k][1]; t.z = v[k][2]; t.w = v[k][3];
        *reinterpret_cast<float4*>(sm + rbase + 4 * k) = t;
    }

    // ---- T2 read: e = (lane>>4)*256 + r16*16 + (lane&15)
    //      addr = 328*(lane>>4) + 20*r16 + (lane&15)   (2-way aliased, free)
    const int base3 = 328 * (lane >> 4) + (lane & 15);
    float w[16];
    #pragma unroll
    for (int r16 = 0; r16 < 16; ++r16)
        w[r16] = sm[base3 + 20 * r16];

    // ---- phase 3: bits {4,5,6,7} over the 16-register index ----
    #pragma unroll
    for (int m = 1; m <= 8; m <<= 1) {
        #pragma unroll
        for (int p = 0; p < 16; ++p) {
            if (!(p & m)) {
                const float u = w[p], t = w[p | m];
                w[p] = u + t; w[p | m] = u - t;
            }
        }
    }

    // ---- epilogue: *1/32, scale, shift; 64B-segment stores ----
    const int ebase = ((lane >> 4) << 8) + (lane & 15);
    float* __restrict__ orow = out + (size_t)row * SIZE;
    #pragma unroll
    for (int r16 = 0; r16 < 16; ++r16) {
        const int e = ebase + 16 * r16;
        const float sc = scale[e];
        const float sh = shift[e];
        __builtin_nontemporal_store(fmaf(w[r16] * INV_SQRT, sc, sh), orow + e);
    }
}

extern "C" void kernel_launch(void* const* d_in, const int* in_sizes, int n_in,
                              void* d_out, int out_size, void* d_ws, size_t ws_size,
                              hipStream_t stream)
{
    const float* x     = (const float*)d_in[0];
    const float* scale = (const float*)d_in[1];
    const float* shift = (const float*)d_in[2];
    float* out         = (float*)d_out;

    const int nrows = in_sizes[0] / SIZE;        // 65536
    const int blocks = (nrows + 3) / 4;          // 4 rows (waves) per block

    fwht1024_kernel<<<blocks, 256, 0, stream>>>(x, scale, shift, out, nrows);
}